// Round 1
// baseline (303.495 us; speedup 1.0000x reference)
//
#include <hip/hip_runtime.h>

// NodeNetwork fused kernel (f32, VALU): 64 nodes/block, 256 threads.
// wave w computes output j-slice w for all 64 nodes -> weight loads wave-uniform (s_load).
constexpr int NB = 64;
constexpr int THREADS = 256;
constexpr int X1S = 132;   // x1 LDS row stride (128 cols, padded, f4-aligned)
constexpr int H1S = 100;   // h1 LDS row stride (96 cols), aliases x1 region
constexpr int X2S = 68;    // x2/h2 LDS row stride (64 cols)

__global__ __launch_bounds__(THREADS) void node_net_kernel(
    const float* __restrict__ feat, const float* __restrict__ hid,
    const float* __restrict__ mail,
    const float* __restrict__ w1a, const float* __restrict__ b1a,
    const float* __restrict__ w1b, const float* __restrict__ b1b,
    const float* __restrict__ w2a, const float* __restrict__ b2a,
    const float* __restrict__ w2b, const float* __restrict__ b2b,
    float* __restrict__ out)
{
    __shared__ float ldsA[NB * X1S];   // x1, later h1
    __shared__ float ldsB[NB * X2S];   // x2, later h2
    __shared__ float ldsS[NB * 4];     // per-sub partial sumsq

    const int t  = threadIdx.x;
    const int n0 = blockIdx.x * NB;

    // ---------- Phase 1: stage x1 = [feat|hid] and mailbox-sum -> x2 ----------
    #pragma unroll
    for (int i = 0; i < 4; ++i) {
        int task = i * THREADS + t;            // 0..1023 = 64 nodes x 16 f4-cols
        int n = task >> 4, c4 = task & 15;
        float4 v = reinterpret_cast<const float4*>(feat)[(n0 + n) * 16 + c4];
        float4 w = reinterpret_cast<const float4*>(hid )[(n0 + n) * 16 + c4];
        float4* dst = reinterpret_cast<float4*>(&ldsA[n * X1S]);
        dst[c4]      = v;
        dst[16 + c4] = w;
    }
    #pragma unroll
    for (int i = 0; i < 4; ++i) {
        int task = i * THREADS + t;
        int n = task >> 4, c4 = task & 15;
        const float4* src = reinterpret_cast<const float4*>(mail)
                          + (size_t)(n0 + n) * 256 + c4;   // [N][16][64] -> 256 f4/node
        float4 a = src[0];
        #pragma unroll
        for (int d = 1; d < 16; ++d) {
            float4 v = src[d * 16];
            a.x += v.x; a.y += v.y; a.z += v.z; a.w += v.w;
        }
        reinterpret_cast<float4*>(&ldsB[n * X2S])[c4] = a;
    }
    __syncthreads();

    const int node = t & 63;
    const int sub  = __builtin_amdgcn_readfirstlane(t >> 6);  // wave id, SGPR-uniform

    // ---------- Phase 2: h1 = relu(x1 @ w1a + b1a), j in [sub*24, sub*24+24) ----------
    float acc1[24];
    {
        const float* b = b1a + sub * 24;
        #pragma unroll
        for (int j = 0; j < 24; ++j) acc1[j] = b[j];
        const float4* xr = reinterpret_cast<const float4*>(&ldsA[node * X1S]);
        #pragma unroll 2
        for (int k4 = 0; k4 < 32; ++k4) {
            float4 x = xr[k4];
            const float* w0 = w1a + (k4 * 4) * 96 + sub * 24;
            #pragma unroll
            for (int j = 0; j < 24; ++j) acc1[j] = fmaf(x.x, w0[j],       acc1[j]);
            #pragma unroll
            for (int j = 0; j < 24; ++j) acc1[j] = fmaf(x.y, w0[96 + j],  acc1[j]);
            #pragma unroll
            for (int j = 0; j < 24; ++j) acc1[j] = fmaf(x.z, w0[192 + j], acc1[j]);
            #pragma unroll
            for (int j = 0; j < 24; ++j) acc1[j] = fmaf(x.w, w0[288 + j], acc1[j]);
        }
    }
    __syncthreads();                     // all x1 reads done; reuse ldsA for h1
    {
        float4* hrow = reinterpret_cast<float4*>(&ldsA[node * H1S + sub * 24]);
        #pragma unroll
        for (int j4 = 0; j4 < 6; ++j4) {
            float4 v;
            v.x = fmaxf(acc1[j4*4+0], 0.f);
            v.y = fmaxf(acc1[j4*4+1], 0.f);
            v.z = fmaxf(acc1[j4*4+2], 0.f);
            v.w = fmaxf(acc1[j4*4+3], 0.f);
            hrow[j4] = v;
        }
    }
    __syncthreads();

    // ---------- Phase 3: r1 = tanh(h1 @ w1b + b1b), j-slice of 16 ----------
    float r1v[16];
    {
        float acc[16];
        const float* b = b1b + sub * 16;
        #pragma unroll
        for (int j = 0; j < 16; ++j) acc[j] = b[j];
        const float4* hr = reinterpret_cast<const float4*>(&ldsA[node * H1S]);
        #pragma unroll 2
        for (int k4 = 0; k4 < 24; ++k4) {
            float4 x = hr[k4];
            const float* w0 = w1b + (k4 * 4) * 64 + sub * 16;
            #pragma unroll
            for (int j = 0; j < 16; ++j) acc[j] = fmaf(x.x, w0[j],       acc[j]);
            #pragma unroll
            for (int j = 0; j < 16; ++j) acc[j] = fmaf(x.y, w0[64 + j],  acc[j]);
            #pragma unroll
            for (int j = 0; j < 16; ++j) acc[j] = fmaf(x.z, w0[128 + j], acc[j]);
            #pragma unroll
            for (int j = 0; j < 16; ++j) acc[j] = fmaf(x.w, w0[192 + j], acc[j]);
        }
        #pragma unroll
        for (int j = 0; j < 16; ++j) r1v[j] = tanhf(acc[j]);
    }

    // ---------- Phase 4: h2 = relu(x2 @ w2a + b2a), j-slice of 16 ----------
    float h2v[16];
    {
        float acc[16];
        const float* b = b2a + sub * 16;
        #pragma unroll
        for (int j = 0; j < 16; ++j) acc[j] = b[j];
        const float4* xr = reinterpret_cast<const float4*>(&ldsB[node * X2S]);
        #pragma unroll 2
        for (int k4 = 0; k4 < 16; ++k4) {
            float4 x = xr[k4];
            const float* w0 = w2a + (k4 * 4) * 64 + sub * 16;
            #pragma unroll
            for (int j = 0; j < 16; ++j) acc[j] = fmaf(x.x, w0[j],       acc[j]);
            #pragma unroll
            for (int j = 0; j < 16; ++j) acc[j] = fmaf(x.y, w0[64 + j],  acc[j]);
            #pragma unroll
            for (int j = 0; j < 16; ++j) acc[j] = fmaf(x.z, w0[128 + j], acc[j]);
            #pragma unroll
            for (int j = 0; j < 16; ++j) acc[j] = fmaf(x.w, w0[192 + j], acc[j]);
        }
        #pragma unroll
        for (int j = 0; j < 16; ++j) h2v[j] = fmaxf(acc[j], 0.f);
    }
    __syncthreads();                     // all x2 reads done; reuse ldsB for h2
    {
        float4* hrow = reinterpret_cast<float4*>(&ldsB[node * X2S + sub * 16]);
        #pragma unroll
        for (int j4 = 0; j4 < 4; ++j4)
            hrow[j4] = make_float4(h2v[j4*4+0], h2v[j4*4+1], h2v[j4*4+2], h2v[j4*4+3]);
    }
    __syncthreads();

    // ---------- Phase 5: r2 = tanh(h2 @ w2b + b2b), j-slice of 16 ----------
    float r2v[16];
    {
        float acc[16];
        const float* b = b2b + sub * 16;
        #pragma unroll
        for (int j = 0; j < 16; ++j) acc[j] = b[j];
        const float4* hr = reinterpret_cast<const float4*>(&ldsB[node * X2S]);
        #pragma unroll 2
        for (int k4 = 0; k4 < 16; ++k4) {
            float4 x = hr[k4];
            const float* w0 = w2b + (k4 * 4) * 64 + sub * 16;
            #pragma unroll
            for (int j = 0; j < 16; ++j) acc[j] = fmaf(x.x, w0[j],       acc[j]);
            #pragma unroll
            for (int j = 0; j < 16; ++j) acc[j] = fmaf(x.y, w0[64 + j],  acc[j]);
            #pragma unroll
            for (int j = 0; j < 16; ++j) acc[j] = fmaf(x.z, w0[128 + j], acc[j]);
            #pragma unroll
            for (int j = 0; j < 16; ++j) acc[j] = fmaf(x.w, w0[192 + j], acc[j]);
        }
        #pragma unroll
        for (int j = 0; j < 16; ++j) r2v[j] = tanhf(acc[j]);
    }

    // ---------- Phase 6: row L2 norm + write ----------
    float s = 0.f;
    #pragma unroll
    for (int j = 0; j < 16; ++j) s += r1v[j] * r1v[j] + r2v[j] * r2v[j];
    ldsS[node * 4 + sub] = s;
    __syncthreads();
    float4 sv = reinterpret_cast<const float4*>(ldsS)[node];
    float rn = rsqrtf(sv.x + sv.y + sv.z + sv.w);

    float* orow = out + (size_t)(n0 + node) * 128;
    float4* o1 = reinterpret_cast<float4*>(orow + sub * 16);
    float4* o2 = reinterpret_cast<float4*>(orow + 64 + sub * 16);
    #pragma unroll
    for (int j4 = 0; j4 < 4; ++j4) {
        o1[j4] = make_float4(r1v[j4*4+0]*rn, r1v[j4*4+1]*rn, r1v[j4*4+2]*rn, r1v[j4*4+3]*rn);
        o2[j4] = make_float4(r2v[j4*4+0]*rn, r2v[j4*4+1]*rn, r2v[j4*4+2]*rn, r2v[j4*4+3]*rn);
    }
}

extern "C" void kernel_launch(void* const* d_in, const int* in_sizes, int n_in,
                              void* d_out, int out_size, void* d_ws, size_t ws_size,
                              hipStream_t stream) {
    const float* feat = (const float*)d_in[0];
    const float* hid  = (const float*)d_in[1];
    const float* mail = (const float*)d_in[2];
    const float* w1a  = (const float*)d_in[3];
    const float* b1a  = (const float*)d_in[4];
    const float* w1b  = (const float*)d_in[5];
    const float* b1b  = (const float*)d_in[6];
    const float* w2a  = (const float*)d_in[7];
    const float* b2a  = (const float*)d_in[8];
    const float* w2b  = (const float*)d_in[9];
    const float* b2b  = (const float*)d_in[10];
    float* out = (float*)d_out;

    const int N = in_sizes[0] / 64;          // 200000
    const int blocks = N / NB;               // 3125 (N divisible by 64)

    node_net_kernel<<<blocks, THREADS, 0, stream>>>(
        feat, hid, mail, w1a, b1a, w1b, b1b, w2a, b2a, w2b, b2b, out);
}